// Round 9
// baseline (287.438 us; speedup 1.0000x reference)
//
#include <hip/hip_runtime.h>

#define F 64
#define H 64
#define NT 256
#define TILE_ROWS 128
#define ITERS 8
#define ROWS_PER_BLOCK (TILE_ROWS * ITERS)   // 1024
#define WPAD 72   // LDS row stride in bf16 elems (144 B): b128 reads land at the 8-words/bank
                  // minimum; b64 epilogue writes ~2-way (free per m136)

typedef __bf16 bf16;
typedef __attribute__((ext_vector_type(8))) __bf16 bf16x8;
typedef __attribute__((ext_vector_type(4))) __bf16 bf16x4;
typedef __attribute__((ext_vector_type(4))) float f32x4;

__device__ __forceinline__ float celu1(float v) {
    // CELU(alpha=1): x>0 ? x : exp(x)-1
    float e = __expf(v) - 1.0f;
    return v > 0.0f ? v : e;
}

// Single kernel, R7-validated internals. Block = one feature f x 1024 rows; 4 waves,
// each owns 32 wave-private hbuf rows per 128-row tile -> one barrier total (bias/wlds).
// Weights: hidden-0 in registers (bf16, converted from fp32 once), hidden-1 in LDS
// (reg-pressure split -> VGPR ~84, no spill; R3-R5 lesson: spills show up as GB-scale
// FETCH_SIZE/WRITE_SIZE scratch traffic and 2-3x slowdown).
// Direct strided x/out (R1/R2-validated pattern): f = bid&63 makes the 16 f-sharers of
// each 64B x/out line temporally adjacent blocks -> L2-friendly.
// All three layers MFMA on C^T[out][batch]: A[m=out][k=in], B[k=in][n=batch],
// D: col=batch=l15, row=out=16m+4q+r. Layer-in is a compensated rank-1 product.
__global__ __launch_bounds__(NT, 4) void mlp64(
    const float* __restrict__ x,      // [B,F]
    const float* __restrict__ w_in,
    const float* __restrict__ b_in,
    const float* __restrict__ w_hid,
    const float* __restrict__ b_hid,
    const float* __restrict__ w_out,
    const float* __restrict__ b_out,
    float* __restrict__ out,          // [B,F]
    int Btot)
{
    const int f    = blockIdx.x & (F - 1);
    const int blk  = blockIdx.x >> 6;
    const int row0 = blk * ROWS_PER_BLOCK;
    const int t    = threadIdx.x;
    const int lane = t & 63;
    const int wave = t >> 6;
    const int l15  = lane & 15;
    const int q    = lane >> 4;
    const int wrow = wave * 32;

    __shared__ __align__(16) bf16 hbuf[TILE_ROWS][WPAD];
    __shared__ __align__(16) bf16 wlds[H][WPAD];          // hidden layer 1 weights [out][in]
    __shared__ __align__(16) float s_bias[3][H];

    // ---- stage hidden-layer-1 weights into LDS (fp32 -> bf16, once per block) ----
    for (int idx = t; idx < 512; idx += NT) {
        const int row = idx >> 3, ch = idx & 7;
        const float* p = w_hid + (((size_t)F + f) << 12) + (row << 6) + (ch << 3);
        float4 a = *(const float4*)p, b = *(const float4*)(p + 4);
        bf16x8 v;
        v[0] = (bf16)a.x; v[1] = (bf16)a.y; v[2] = (bf16)a.z; v[3] = (bf16)a.w;
        v[4] = (bf16)b.x; v[5] = (bf16)b.y; v[6] = (bf16)b.z; v[7] = (bf16)b.w;
        *(bf16x8*)&wlds[row][ch * 8] = v;
    }
    if (t < H)           s_bias[0][t]         = b_in[f * H + t];
    else if (t < 2 * H)  s_bias[1][t - H]     = b_hid[(0 * F + f) * H + (t - H)];
    else if (t < 3 * H)  s_bias[2][t - 2 * H] = b_hid[(1 * F + f) * H + (t - 2 * H)];
    __syncthreads();

    // ---- hidden-layer-0 weights in registers (fp32 -> bf16) ----
    bf16x8 Aw0[4][2];            // A[m=16m+l15][k=32kk+q*8+j]
    #pragma unroll
    for (int m = 0; m < 4; ++m) {
        const float* p = w_hid + ((size_t)f << 12) + (m * 16 + l15) * 64 + q * 8;
        #pragma unroll
        for (int kk = 0; kk < 2; ++kk) {
            float4 a = *(const float4*)(p + kk * 32), b = *(const float4*)(p + kk * 32 + 4);
            bf16x8 v;
            v[0] = (bf16)a.x; v[1] = (bf16)a.y; v[2] = (bf16)a.z; v[3] = (bf16)a.w;
            v[4] = (bf16)b.x; v[5] = (bf16)b.y; v[6] = (bf16)b.z; v[7] = (bf16)b.w;
            Aw0[m][kk] = v;
        }
    }

    bf16x8 A1[4];                // layer-in A frags: quad 0 holds (w_hi, w_lo, w_hi, 0...)
    #pragma unroll
    for (int m = 0; m < 4; ++m) {
        float w  = w_in[f * H + m * 16 + l15];
        bf16 hi  = (bf16)w;
        bf16 lo  = (bf16)(w - (float)hi);
        bf16x8 v = {};
        if (q == 0) { v[0] = hi; v[1] = lo; v[2] = hi; }
        A1[m] = v;
    }

    f32x4 wo4[4];
    #pragma unroll
    for (int m = 0; m < 4; ++m)
        wo4[m] = *(const f32x4*)(w_out + f * H + m * 16 + q * 4);
    const float bo = b_out[f];

    // strided 4B x loads; sharers are temporally adjacent blocks -> L2 hits
    float xc0 = x[(size_t)(row0 + wrow + l15) * F + f];
    float xc1 = x[(size_t)(row0 + wrow + 16 + l15) * F + f];

    #pragma unroll 1
    for (int it = 0; it < ITERS; ++it) {
        const int rbase = row0 + it * TILE_ROWS + wrow;

        // B1 frags: quad 0 holds (x_hi, x_hi, x_lo, 0...)
        bf16x8 B1[2];
        {
            bf16 h0 = (bf16)xc0, h1 = (bf16)xc1;
            bf16 l0 = (bf16)(xc0 - (float)h0), l1 = (bf16)(xc1 - (float)h1);
            bf16x8 v0 = {}, v1 = {};
            if (q == 0) { v0[0] = h0; v0[1] = h0; v0[2] = l0;
                          v1[0] = h1; v1[1] = h1; v1[2] = l1; }
            B1[0] = v0; B1[1] = v1;
        }
        float xn0 = 0.0f, xn1 = 0.0f;
        if (it + 1 < ITERS) {
            xn0 = x[(size_t)(rbase + TILE_ROWS + l15) * F + f];
            xn1 = x[(size_t)(rbase + TILE_ROWS + 16 + l15) * F + f];
        }

        // ---- layer in->H ----
        #pragma unroll
        for (int m = 0; m < 4; ++m) {
            f32x4 c0 = *(const f32x4*)&s_bias[0][m * 16 + q * 4];
            f32x4 a0 = __builtin_amdgcn_mfma_f32_16x16x32_bf16(A1[m], B1[0], c0, 0, 0, 0);
            f32x4 a1 = __builtin_amdgcn_mfma_f32_16x16x32_bf16(A1[m], B1[1], c0, 0, 0, 0);
            bf16x4 o0, o1;
            #pragma unroll
            for (int rr = 0; rr < 4; ++rr) { o0[rr] = (bf16)celu1(a0[rr]); o1[rr] = (bf16)celu1(a1[rr]); }
            *(bf16x4*)&hbuf[wrow + l15][m * 16 + q * 4]      = o0;
            *(bf16x4*)&hbuf[wrow + 16 + l15][m * 16 + q * 4] = o1;
        }

        // ---- hidden layer 0 (register weights) ----
        {
            bf16x8 Bh[2][2];
            #pragma unroll
            for (int n = 0; n < 2; ++n)
                #pragma unroll
                for (int kk = 0; kk < 2; ++kk)
                    Bh[n][kk] = *(const bf16x8*)&hbuf[wrow + n * 16 + l15][kk * 32 + q * 8];
            #pragma unroll
            for (int m = 0; m < 4; ++m) {
                f32x4 c0 = *(const f32x4*)&s_bias[1][m * 16 + q * 4];
                f32x4 a0 = __builtin_amdgcn_mfma_f32_16x16x32_bf16(Aw0[m][0], Bh[0][0], c0, 0, 0, 0);
                a0       = __builtin_amdgcn_mfma_f32_16x16x32_bf16(Aw0[m][1], Bh[0][1], a0, 0, 0, 0);
                f32x4 a1 = __builtin_amdgcn_mfma_f32_16x16x32_bf16(Aw0[m][0], Bh[1][0], c0, 0, 0, 0);
                a1       = __builtin_amdgcn_mfma_f32_16x16x32_bf16(Aw0[m][1], Bh[1][1], a1, 0, 0, 0);
                bf16x4 o0, o1;
                #pragma unroll
                for (int rr = 0; rr < 4; ++rr) { o0[rr] = (bf16)celu1(a0[rr]); o1[rr] = (bf16)celu1(a1[rr]); }
                *(bf16x4*)&hbuf[wrow + l15][m * 16 + q * 4]      = o0;
                *(bf16x4*)&hbuf[wrow + 16 + l15][m * 16 + q * 4] = o1;
            }
        }

        // ---- hidden layer 1 (LDS weights) + output dot in registers ----
        {
            bf16x8 Bh[2][2];
            #pragma unroll
            for (int n = 0; n < 2; ++n)
                #pragma unroll
                for (int kk = 0; kk < 2; ++kk)
                    Bh[n][kk] = *(const bf16x8*)&hbuf[wrow + n * 16 + l15][kk * 32 + q * 8];
            float s0 = 0.0f, s1 = 0.0f;
            #pragma unroll
            for (int m = 0; m < 4; ++m) {
                bf16x8 Awt0 = *(const bf16x8*)&wlds[m * 16 + l15][q * 8];
                bf16x8 Awt1 = *(const bf16x8*)&wlds[m * 16 + l15][32 + q * 8];
                f32x4 c0 = *(const f32x4*)&s_bias[2][m * 16 + q * 4];
                f32x4 a0 = __builtin_amdgcn_mfma_f32_16x16x32_bf16(Awt0, Bh[0][0], c0, 0, 0, 0);
                a0       = __builtin_amdgcn_mfma_f32_16x16x32_bf16(Awt1, Bh[0][1], a0, 0, 0, 0);
                f32x4 a1 = __builtin_amdgcn_mfma_f32_16x16x32_bf16(Awt0, Bh[1][0], c0, 0, 0, 0);
                a1       = __builtin_amdgcn_mfma_f32_16x16x32_bf16(Awt1, Bh[1][1], a1, 0, 0, 0);
                #pragma unroll
                for (int rr = 0; rr < 4; ++rr) {
                    s0 = fmaf(celu1(a0[rr]), wo4[m][rr], s0);
                    s1 = fmaf(celu1(a1[rr]), wo4[m][rr], s1);
                }
            }
            s0 += __shfl_xor(s0, 16, 64);
            s0 += __shfl_xor(s0, 32, 64);
            s1 += __shfl_xor(s1, 16, 64);
            s1 += __shfl_xor(s1, 32, 64);
            if (q == 0) {
                out[(size_t)(rbase + l15) * F + f]      = s0 + bo;
                out[(size_t)(rbase + 16 + l15) * F + f] = s1 + bo;
            }
        }

        xc0 = xn0; xc1 = xn1;
    }
}

extern "C" void kernel_launch(void* const* d_in, const int* in_sizes, int n_in,
                              void* d_out, int out_size, void* d_ws, size_t ws_size,
                              hipStream_t stream) {
    const float* x     = (const float*)d_in[0];
    const float* w_in  = (const float*)d_in[1];
    const float* b_in  = (const float*)d_in[2];
    const float* w_hid = (const float*)d_in[3];
    const float* b_hid = (const float*)d_in[4];
    const float* w_out = (const float*)d_in[5];
    const float* b_out = (const float*)d_in[6];
    float* out = (float*)d_out;

    const int Btot = in_sizes[0] / F;                       // 32768
    dim3 grid((unsigned)((Btot / ROWS_PER_BLOCK) * F));     // 2048 blocks
    dim3 block(NT);
    mlp64<<<grid, block, 0, stream>>>(x, w_in, b_in, w_hid, b_hid, w_out, b_out, out, Btot);
}

// Round 10
// 187.643 us; speedup vs baseline: 1.5318x; 1.5318x over previous
//
#include <hip/hip_runtime.h>

#define F 64
#define H 64
#define NT 256
#define TILE_ROWS 128
#define ITERS 8
#define ROWS_PER_BLOCK (TILE_ROWS * ITERS)   // 1024
#define WPAD 72   // LDS row stride in bf16 elems (144 B): b128 reads land at the 8-words/bank
                  // minimum; b64 epilogue writes ~2-way (free per m136)

typedef __bf16 bf16;
typedef __attribute__((ext_vector_type(8))) __bf16 bf16x8;
typedef __attribute__((ext_vector_type(4))) __bf16 bf16x4;
typedef __attribute__((ext_vector_type(4))) float f32x4;

__device__ __forceinline__ float celu1(float v) {
    // CELU(alpha=1): x>0 ? x : exp(x)-1
    float e = __expf(v) - 1.0f;
    return v > 0.0f ? v : e;
}

// Single kernel, R7-validated internals. Block = one feature f x 1024 rows; 4 waves,
// each owns 32 wave-private hbuf rows per 128-row tile -> one barrier total (bias/wlds).
// Weights: hidden-0 in registers (bf16, converted from fp32 once), hidden-1 in LDS.
// __launch_bounds__(256,3): cap 170 regs. DO NOT raise to min-waves=4 (cap 128):
// measured three times (R4/R5/R9) that this live set then spills -- signature is
// reported VGPR_Count==64 and FETCH_SIZE in the 0.5-1 GB range from scratch traffic.
// Direct strided x/out (R1/R2-validated: ~33 MB fetch / ~65 MB write at 16384-block
// granularity); f = bid&63 keeps the 16 f-sharers of each 64B line temporally adjacent.
// All three layers MFMA on C^T[out][batch]: A[m=out][k=in], B[k=in][n=batch],
// D: col=batch=l15, row=out=16m+4q+r. Layer-in is a compensated rank-1 product.
__global__ __launch_bounds__(NT, 3) void mlp64(
    const float* __restrict__ x,      // [B,F]
    const float* __restrict__ w_in,
    const float* __restrict__ b_in,
    const float* __restrict__ w_hid,
    const float* __restrict__ b_hid,
    const float* __restrict__ w_out,
    const float* __restrict__ b_out,
    float* __restrict__ out,          // [B,F]
    int Btot)
{
    const int f    = blockIdx.x & (F - 1);
    const int blk  = blockIdx.x >> 6;
    const int row0 = blk * ROWS_PER_BLOCK;
    const int t    = threadIdx.x;
    const int lane = t & 63;
    const int wave = t >> 6;
    const int l15  = lane & 15;
    const int q    = lane >> 4;
    const int wrow = wave * 32;

    __shared__ __align__(16) bf16 hbuf[TILE_ROWS][WPAD];
    __shared__ __align__(16) bf16 wlds[H][WPAD];          // hidden layer 1 weights [out][in]
    __shared__ __align__(16) float s_bias[3][H];

    // ---- stage hidden-layer-1 weights into LDS (fp32 -> bf16, once per block) ----
    for (int idx = t; idx < 512; idx += NT) {
        const int row = idx >> 3, ch = idx & 7;
        const float* p = w_hid + (((size_t)F + f) << 12) + (row << 6) + (ch << 3);
        float4 a = *(const float4*)p, b = *(const float4*)(p + 4);
        bf16x8 v;
        v[0] = (bf16)a.x; v[1] = (bf16)a.y; v[2] = (bf16)a.z; v[3] = (bf16)a.w;
        v[4] = (bf16)b.x; v[5] = (bf16)b.y; v[6] = (bf16)b.z; v[7] = (bf16)b.w;
        *(bf16x8*)&wlds[row][ch * 8] = v;
    }
    if (t < H)           s_bias[0][t]         = b_in[f * H + t];
    else if (t < 2 * H)  s_bias[1][t - H]     = b_hid[(0 * F + f) * H + (t - H)];
    else if (t < 3 * H)  s_bias[2][t - 2 * H] = b_hid[(1 * F + f) * H + (t - 2 * H)];
    __syncthreads();

    // ---- hidden-layer-0 weights in registers (fp32 -> bf16) ----
    bf16x8 Aw0[4][2];            // A[m=16m+l15][k=32kk+q*8+j]
    #pragma unroll
    for (int m = 0; m < 4; ++m) {
        const float* p = w_hid + ((size_t)f << 12) + (m * 16 + l15) * 64 + q * 8;
        #pragma unroll
        for (int kk = 0; kk < 2; ++kk) {
            float4 a = *(const float4*)(p + kk * 32), b = *(const float4*)(p + kk * 32 + 4);
            bf16x8 v;
            v[0] = (bf16)a.x; v[1] = (bf16)a.y; v[2] = (bf16)a.z; v[3] = (bf16)a.w;
            v[4] = (bf16)b.x; v[5] = (bf16)b.y; v[6] = (bf16)b.z; v[7] = (bf16)b.w;
            Aw0[m][kk] = v;
        }
    }

    bf16x8 A1[4];                // layer-in A frags: quad 0 holds (w_hi, w_lo, w_hi, 0...)
    #pragma unroll
    for (int m = 0; m < 4; ++m) {
        float w  = w_in[f * H + m * 16 + l15];
        bf16 hi  = (bf16)w;
        bf16 lo  = (bf16)(w - (float)hi);
        bf16x8 v = {};
        if (q == 0) { v[0] = hi; v[1] = lo; v[2] = hi; }
        A1[m] = v;
    }

    f32x4 wo4[4];
    #pragma unroll
    for (int m = 0; m < 4; ++m)
        wo4[m] = *(const f32x4*)(w_out + f * H + m * 16 + q * 4);
    const float bo = b_out[f];

    // strided 4B x loads; sharers are temporally adjacent blocks -> L2 hits
    float xc0 = x[(size_t)(row0 + wrow + l15) * F + f];
    float xc1 = x[(size_t)(row0 + wrow + 16 + l15) * F + f];

    #pragma unroll 1
    for (int it = 0; it < ITERS; ++it) {
        const int rbase = row0 + it * TILE_ROWS + wrow;

        // B1 frags: quad 0 holds (x_hi, x_hi, x_lo, 0...)
        bf16x8 B1[2];
        {
            bf16 h0 = (bf16)xc0, h1 = (bf16)xc1;
            bf16 l0 = (bf16)(xc0 - (float)h0), l1 = (bf16)(xc1 - (float)h1);
            bf16x8 v0 = {}, v1 = {};
            if (q == 0) { v0[0] = h0; v0[1] = h0; v0[2] = l0;
                          v1[0] = h1; v1[1] = h1; v1[2] = l1; }
            B1[0] = v0; B1[1] = v1;
        }
        float xn0 = 0.0f, xn1 = 0.0f;
        if (it + 1 < ITERS) {
            xn0 = x[(size_t)(rbase + TILE_ROWS + l15) * F + f];
            xn1 = x[(size_t)(rbase + TILE_ROWS + 16 + l15) * F + f];
        }

        // ---- layer in->H ----
        #pragma unroll
        for (int m = 0; m < 4; ++m) {
            f32x4 c0 = *(const f32x4*)&s_bias[0][m * 16 + q * 4];
            f32x4 a0 = __builtin_amdgcn_mfma_f32_16x16x32_bf16(A1[m], B1[0], c0, 0, 0, 0);
            f32x4 a1 = __builtin_amdgcn_mfma_f32_16x16x32_bf16(A1[m], B1[1], c0, 0, 0, 0);
            bf16x4 o0, o1;
            #pragma unroll
            for (int rr = 0; rr < 4; ++rr) { o0[rr] = (bf16)celu1(a0[rr]); o1[rr] = (bf16)celu1(a1[rr]); }
            *(bf16x4*)&hbuf[wrow + l15][m * 16 + q * 4]      = o0;
            *(bf16x4*)&hbuf[wrow + 16 + l15][m * 16 + q * 4] = o1;
        }

        // ---- hidden layer 0 (register weights) ----
        {
            bf16x8 Bh[2][2];
            #pragma unroll
            for (int n = 0; n < 2; ++n)
                #pragma unroll
                for (int kk = 0; kk < 2; ++kk)
                    Bh[n][kk] = *(const bf16x8*)&hbuf[wrow + n * 16 + l15][kk * 32 + q * 8];
            #pragma unroll
            for (int m = 0; m < 4; ++m) {
                f32x4 c0 = *(const f32x4*)&s_bias[1][m * 16 + q * 4];
                f32x4 a0 = __builtin_amdgcn_mfma_f32_16x16x32_bf16(Aw0[m][0], Bh[0][0], c0, 0, 0, 0);
                a0       = __builtin_amdgcn_mfma_f32_16x16x32_bf16(Aw0[m][1], Bh[0][1], a0, 0, 0, 0);
                f32x4 a1 = __builtin_amdgcn_mfma_f32_16x16x32_bf16(Aw0[m][0], Bh[1][0], c0, 0, 0, 0);
                a1       = __builtin_amdgcn_mfma_f32_16x16x32_bf16(Aw0[m][1], Bh[1][1], a1, 0, 0, 0);
                bf16x4 o0, o1;
                #pragma unroll
                for (int rr = 0; rr < 4; ++rr) { o0[rr] = (bf16)celu1(a0[rr]); o1[rr] = (bf16)celu1(a1[rr]); }
                *(bf16x4*)&hbuf[wrow + l15][m * 16 + q * 4]      = o0;
                *(bf16x4*)&hbuf[wrow + 16 + l15][m * 16 + q * 4] = o1;
            }
        }

        // ---- hidden layer 1 (LDS weights) + output dot in registers ----
        {
            bf16x8 Bh[2][2];
            #pragma unroll
            for (int n = 0; n < 2; ++n)
                #pragma unroll
                for (int kk = 0; kk < 2; ++kk)
                    Bh[n][kk] = *(const bf16x8*)&hbuf[wrow + n * 16 + l15][kk * 32 + q * 8];
            float s0 = 0.0f, s1 = 0.0f;
            #pragma unroll
            for (int m = 0; m < 4; ++m) {
                bf16x8 Awt0 = *(const bf16x8*)&wlds[m * 16 + l15][q * 8];
                bf16x8 Awt1 = *(const bf16x8*)&wlds[m * 16 + l15][32 + q * 8];
                f32x4 c0 = *(const f32x4*)&s_bias[2][m * 16 + q * 4];
                f32x4 a0 = __builtin_amdgcn_mfma_f32_16x16x32_bf16(Awt0, Bh[0][0], c0, 0, 0, 0);
                a0       = __builtin_amdgcn_mfma_f32_16x16x32_bf16(Awt1, Bh[0][1], a0, 0, 0, 0);
                f32x4 a1 = __builtin_amdgcn_mfma_f32_16x16x32_bf16(Awt0, Bh[1][0], c0, 0, 0, 0);
                a1       = __builtin_amdgcn_mfma_f32_16x16x32_bf16(Awt1, Bh[1][1], a1, 0, 0, 0);
                #pragma unroll
                for (int rr = 0; rr < 4; ++rr) {
                    s0 = fmaf(celu1(a0[rr]), wo4[m][rr], s0);
                    s1 = fmaf(celu1(a1[rr]), wo4[m][rr], s1);
                }
            }
            s0 += __shfl_xor(s0, 16, 64);
            s0 += __shfl_xor(s0, 32, 64);
            s1 += __shfl_xor(s1, 16, 64);
            s1 += __shfl_xor(s1, 32, 64);
            if (q == 0) {
                out[(size_t)(rbase + l15) * F + f]      = s0 + bo;
                out[(size_t)(rbase + 16 + l15) * F + f] = s1 + bo;
            }
        }

        xc0 = xn0; xc1 = xn1;
    }
}

extern "C" void kernel_launch(void* const* d_in, const int* in_sizes, int n_in,
                              void* d_out, int out_size, void* d_ws, size_t ws_size,
                              hipStream_t stream) {
    const float* x     = (const float*)d_in[0];
    const float* w_in  = (const float*)d_in[1];
    const float* b_in  = (const float*)d_in[2];
    const float* w_hid = (const float*)d_in[3];
    const float* b_hid = (const float*)d_in[4];
    const float* w_out = (const float*)d_in[5];
    const float* b_out = (const float*)d_in[6];
    float* out = (float*)d_out;

    const int Btot = in_sizes[0] / F;                       // 32768
    dim3 grid((unsigned)((Btot / ROWS_PER_BLOCK) * F));     // 2048 blocks
    dim3 block(NT);
    mlp64<<<grid, block, 0, stream>>>(x, w_in, b_in, w_hid, b_hid, w_out, b_out, out, Btot);
}

// Round 11
// 181.814 us; speedup vs baseline: 1.5810x; 1.0321x over previous
//
#include <hip/hip_runtime.h>

#define F 64
#define H 64
#define NT 256
#define TILE_ROWS 256     // per block per iteration: 4 waves x 64 rows
#define ITERS 4
#define ROWS_PER_BLOCK (TILE_ROWS * ITERS)   // 1024
#define WPAD 72   // LDS row stride in bf16 elems (144 B): b128 reads and b64 writes at min bank cycles

typedef __bf16 bf16;
typedef __attribute__((ext_vector_type(8))) __bf16 bf16x8;
typedef __attribute__((ext_vector_type(4))) __bf16 bf16x4;
typedef __attribute__((ext_vector_type(4))) float f32x4;

__device__ __forceinline__ float celu1(float v) {
    // CELU(alpha=1): x>0 ? x : exp(x)-1
    float e = __expf(v) - 1.0f;
    return v > 0.0f ? v : e;
}

// Single kernel. Block = one feature f x 1024 rows; 4 waves, each owns a 64-row
// wave-private hbuf slice per 256-row tile (4 independent 16-row MFMA chains per wave
// -> 2x the ILP of the R10 32-row version, attacking the 37% stall fraction).
// Weights: hidden-0 in registers (bf16), hidden-1 in LDS. __launch_bounds__(256,3):
// cap 170 regs. DO NOT raise to min-waves=4 (cap 128): measured 3x (R4/R5/R9) that
// this live set then spills -- signature is reported VGPR_Count==64 and FETCH_SIZE
// in the 0.5-1 GB range (scratch traffic). One barrier total (bias/wlds staging).
// All three layers MFMA on C^T[out][batch]: A[m=out][k=in], B[k=in][n=batch],
// D: col=batch=l15, row=out=16m+4q+rr. Layer-in is a compensated rank-1 product
// (w_hi,w_lo,w_hi)x(x_hi,x_hi,x_lo) in k-slots 0..2.
__global__ __launch_bounds__(NT, 3) void mlp64(
    const float* __restrict__ x,      // [B,F]
    const float* __restrict__ w_in,
    const float* __restrict__ b_in,
    const float* __restrict__ w_hid,
    const float* __restrict__ b_hid,
    const float* __restrict__ w_out,
    const float* __restrict__ b_out,
    float* __restrict__ out,          // [B,F]
    int Btot)
{
    const int f    = blockIdx.x & (F - 1);
    const int blk  = blockIdx.x >> 6;
    const int row0 = blk * ROWS_PER_BLOCK;
    const int t    = threadIdx.x;
    const int lane = t & 63;
    const int wave = t >> 6;
    const int l15  = lane & 15;
    const int q    = lane >> 4;
    const int wrow = wave * 64;       // 64-row wave-private slice

    __shared__ __align__(16) bf16 hbuf[TILE_ROWS][WPAD];   // 36.9 KB
    __shared__ __align__(16) bf16 wlds[H][WPAD];           // hidden layer 1 weights [out][in]
    __shared__ __align__(16) float s_bias[3][H];

    // ---- stage hidden-layer-1 weights into LDS (fp32 -> bf16, once per block) ----
    for (int idx = t; idx < 512; idx += NT) {
        const int row = idx >> 3, ch = idx & 7;
        const float* p = w_hid + (((size_t)F + f) << 12) + (row << 6) + (ch << 3);
        float4 a = *(const float4*)p, b = *(const float4*)(p + 4);
        bf16x8 v;
        v[0] = (bf16)a.x; v[1] = (bf16)a.y; v[2] = (bf16)a.z; v[3] = (bf16)a.w;
        v[4] = (bf16)b.x; v[5] = (bf16)b.y; v[6] = (bf16)b.z; v[7] = (bf16)b.w;
        *(bf16x8*)&wlds[row][ch * 8] = v;
    }
    if (t < H)           s_bias[0][t]         = b_in[f * H + t];
    else if (t < 2 * H)  s_bias[1][t - H]     = b_hid[(0 * F + f) * H + (t - H)];
    else if (t < 3 * H)  s_bias[2][t - 2 * H] = b_hid[(1 * F + f) * H + (t - 2 * H)];
    __syncthreads();

    // ---- hidden-layer-0 weights in registers (fp32 -> bf16) ----
    bf16x8 Aw0[4][2];            // A[m=16m+l15][k=32kk+q*8+j]
    #pragma unroll
    for (int m = 0; m < 4; ++m) {
        const float* p = w_hid + ((size_t)f << 12) + (m * 16 + l15) * 64 + q * 8;
        #pragma unroll
        for (int kk = 0; kk < 2; ++kk) {
            float4 a = *(const float4*)(p + kk * 32), b = *(const float4*)(p + kk * 32 + 4);
            bf16x8 v;
            v[0] = (bf16)a.x; v[1] = (bf16)a.y; v[2] = (bf16)a.z; v[3] = (bf16)a.w;
            v[4] = (bf16)b.x; v[5] = (bf16)b.y; v[6] = (bf16)b.z; v[7] = (bf16)b.w;
            Aw0[m][kk] = v;
        }
    }

    bf16x8 A1[4];                // layer-in A frags: quad 0 holds (w_hi, w_lo, w_hi, 0...)
    #pragma unroll
    for (int m = 0; m < 4; ++m) {
        float w  = w_in[f * H + m * 16 + l15];
        bf16 hi  = (bf16)w;
        bf16 lo  = (bf16)(w - (float)hi);
        bf16x8 v = {};
        if (q == 0) { v[0] = hi; v[1] = lo; v[2] = hi; }
        A1[m] = v;
    }

    f32x4 wo4[4];
    #pragma unroll
    for (int m = 0; m < 4; ++m)
        wo4[m] = *(const f32x4*)(w_out + f * H + m * 16 + q * 4);
    const float bo = b_out[f];

    // strided 4B x loads; sharers are temporally adjacent blocks -> L2 hits
    float xc[4], xn[4];
    #pragma unroll
    for (int n = 0; n < 4; ++n)
        xc[n] = x[(size_t)(row0 + wrow + n * 16 + l15) * F + f];

    #pragma unroll 1
    for (int it = 0; it < ITERS; ++it) {
        const int rbase = row0 + it * TILE_ROWS + wrow;

        // B1 frags: quad 0 holds (x_hi, x_hi, x_lo, 0...)
        bf16x8 B1[4];
        #pragma unroll
        for (int n = 0; n < 4; ++n) {
            bf16 hh = (bf16)xc[n];
            bf16 ll = (bf16)(xc[n] - (float)hh);
            bf16x8 v = {};
            if (q == 0) { v[0] = hh; v[1] = hh; v[2] = ll; }
            B1[n] = v;
        }
        #pragma unroll
        for (int n = 0; n < 4; ++n)
            xn[n] = (it + 1 < ITERS)
                  ? x[(size_t)(rbase + TILE_ROWS + n * 16 + l15) * F + f] : 0.0f;

        // ---- layer in->H: 4 independent chains per m ----
        #pragma unroll
        for (int m = 0; m < 4; ++m) {
            f32x4 c0 = *(const f32x4*)&s_bias[0][m * 16 + q * 4];
            f32x4 a[4];
            #pragma unroll
            for (int n = 0; n < 4; ++n)
                a[n] = __builtin_amdgcn_mfma_f32_16x16x32_bf16(A1[m], B1[n], c0, 0, 0, 0);
            #pragma unroll
            for (int n = 0; n < 4; ++n) {
                bf16x4 o;
                #pragma unroll
                for (int rr = 0; rr < 4; ++rr) o[rr] = (bf16)celu1(a[n][rr]);
                *(bf16x4*)&hbuf[wrow + n * 16 + l15][m * 16 + q * 4] = o;
            }
        }

        // ---- hidden layer 0 (register weights) ----
        {
            bf16x8 Bh[4][2];
            #pragma unroll
            for (int n = 0; n < 4; ++n)
                #pragma unroll
                for (int kk = 0; kk < 2; ++kk)
                    Bh[n][kk] = *(const bf16x8*)&hbuf[wrow + n * 16 + l15][kk * 32 + q * 8];
            #pragma unroll
            for (int m = 0; m < 4; ++m) {
                f32x4 c0 = *(const f32x4*)&s_bias[1][m * 16 + q * 4];
                f32x4 a[4];
                #pragma unroll
                for (int n = 0; n < 4; ++n) {
                    a[n] = __builtin_amdgcn_mfma_f32_16x16x32_bf16(Aw0[m][0], Bh[n][0], c0, 0, 0, 0);
                    a[n] = __builtin_amdgcn_mfma_f32_16x16x32_bf16(Aw0[m][1], Bh[n][1], a[n], 0, 0, 0);
                }
                #pragma unroll
                for (int n = 0; n < 4; ++n) {
                    bf16x4 o;
                    #pragma unroll
                    for (int rr = 0; rr < 4; ++rr) o[rr] = (bf16)celu1(a[n][rr]);
                    *(bf16x4*)&hbuf[wrow + n * 16 + l15][m * 16 + q * 4] = o;
                }
            }
        }

        // ---- hidden layer 1 (LDS weights) + output dot in registers ----
        {
            bf16x8 Bh[4][2];
            #pragma unroll
            for (int n = 0; n < 4; ++n)
                #pragma unroll
                for (int kk = 0; kk < 2; ++kk)
                    Bh[n][kk] = *(const bf16x8*)&hbuf[wrow + n * 16 + l15][kk * 32 + q * 8];
            float s[4] = {0.0f, 0.0f, 0.0f, 0.0f};
            #pragma unroll
            for (int m = 0; m < 4; ++m) {
                bf16x8 Awt0 = *(const bf16x8*)&wlds[m * 16 + l15][q * 8];
                bf16x8 Awt1 = *(const bf16x8*)&wlds[m * 16 + l15][32 + q * 8];
                f32x4 c0 = *(const f32x4*)&s_bias[2][m * 16 + q * 4];
                f32x4 a[4];
                #pragma unroll
                for (int n = 0; n < 4; ++n) {
                    a[n] = __builtin_amdgcn_mfma_f32_16x16x32_bf16(Awt0, Bh[n][0], c0, 0, 0, 0);
                    a[n] = __builtin_amdgcn_mfma_f32_16x16x32_bf16(Awt1, Bh[n][1], a[n], 0, 0, 0);
                }
                #pragma unroll
                for (int n = 0; n < 4; ++n)
                    #pragma unroll
                    for (int rr = 0; rr < 4; ++rr)
                        s[n] = fmaf(celu1(a[n][rr]), wo4[m][rr], s[n]);
            }
            #pragma unroll
            for (int n = 0; n < 4; ++n) {
                s[n] += __shfl_xor(s[n], 16, 64);
                s[n] += __shfl_xor(s[n], 32, 64);
            }
            if (q == 0) {
                #pragma unroll
                for (int n = 0; n < 4; ++n)
                    out[(size_t)(rbase + n * 16 + l15) * F + f] = s[n] + bo;
            }
        }

        #pragma unroll
        for (int n = 0; n < 4; ++n) xc[n] = xn[n];
    }
}

extern "C" void kernel_launch(void* const* d_in, const int* in_sizes, int n_in,
                              void* d_out, int out_size, void* d_ws, size_t ws_size,
                              hipStream_t stream) {
    const float* x     = (const float*)d_in[0];
    const float* w_in  = (const float*)d_in[1];
    const float* b_in  = (const float*)d_in[2];
    const float* w_hid = (const float*)d_in[3];
    const float* b_hid = (const float*)d_in[4];
    const float* w_out = (const float*)d_in[5];
    const float* b_out = (const float*)d_in[6];
    float* out = (float*)d_out;

    const int Btot = in_sizes[0] / F;                       // 32768
    dim3 grid((unsigned)((Btot / ROWS_PER_BLOCK) * F));     // 2048 blocks
    dim3 block(NT);
    mlp64<<<grid, block, 0, stream>>>(x, w_in, b_in, w_hid, b_hid, w_out, b_out, out, Btot);
}